// Round 12
// baseline (335.362 us; speedup 1.0000x reference)
//
#include <hip/hip_runtime.h>
#include <hip/hip_bf16.h>

// Problem constants
#define B_    512
#define HIST_ 8
#define PRED_ 24
#define CITY_ 184
#define FEAT_ 13
#define HID_  32
#define BC_   (B_*CITY_)   // 94208 = 1472 * 64
#define FLAG_OFF 7168

// ws (float) layout (written by prep_all; rows PERMUTED, see below):
//   [0..4095]      Wh2[p*32+k] : W_hh + a0 (x) W_out   (t>=1 path)
//   [4096..6143]   Wf [p*16+f] : f<13: W_x[:,1+f]; f==13: bg2 (bias column,
//                                feature elem 13 is constant 1.0); f=14,15: 0
//   [6272..6399]   a0 [p]      : W_x[:,0]              (t==0)
//   [6528..6559]   wout[u]     : unit-indexed
//   [6560]         bout
//   [7168]         dtype flag: 0.0f = bf16 inputs, 1.0f = fp32 inputs
//
// *** WS BUDGET RULE (R10): never write ws beyond index 7168 (workspace is
// ~8192 floats).  Fragment cache lives in per-block LDS. ***
//
// Row permutation: gate-row j = 32*gate + u stored at p = 16*tt + 4*(u>>3)
// + (psi&3), psi = u&7, tt = 2*gate + (psi>>2).  D-tile at lane (rho,q)
// holds i/f/g/o of units {8q..8q+7}, seq rho == the B k-slice the lane
// supplies next step.  h never leaves the lane.
//
// NOTE (R4): VGPR cap < working set -> spill catastrophe. Watch WRITE_SIZE.
// NOTE (R5): s_setprio corrupted results.  Never again.
// NOTE (R6): quad-rcp/inv4 regressed.  Plain sigf/tanhf_.
// NOTE (R8): facc software-pipeline regressed.  Reverted.
// NOTE (R9): keep()-pinning NULL: compiler remats weights every step.
// NOTE (R11): fragment planes packed in LDS once/block -> remat is cheap
// ds_read (conflict-free), zero conversion VALU.  f32 163->150.
// NOTE (R12): occupancy stuck at 2 waves/SIMD despite VGPR=84 => unified
// VGPR+AGPR allocation (acc[8]=32 + MFMA copies) is the binding resource.
// Split-half processing (4 live acc tiles, not 8) + cap 170 on BOTH kernels
// targets 3 waves/SIMD.  Per-cell math identical -> bit-identical output.

struct TrueT  { static constexpr bool value = true;  };
struct FalseT { static constexpr bool value = false; };

typedef _Float16 v8hf __attribute__((ext_vector_type(8)));
typedef _Float16 v4hf __attribute__((ext_vector_type(4)));
typedef _Float16 v2hf __attribute__((ext_vector_type(2)));
typedef float    v4f  __attribute__((ext_vector_type(4)));

__device__ __forceinline__ v2hf pkrtz(float a, float b) {
    return __builtin_bit_cast(v2hf, __builtin_amdgcn_cvt_pkrtz(a, b));
}
__device__ __forceinline__ unsigned pack2(_Float16 a, _Float16 b) {
    v2hf v; v[0] = a; v[1] = b;
    return __builtin_bit_cast(unsigned, v);
}

__device__ __forceinline__ float rcp_(float x) { return __builtin_amdgcn_rcpf(x); }
__device__ __forceinline__ float sigf(float x) { return rcp_(1.0f + __expf(-x)); }
__device__ __forceinline__ float tanhf_(float x) {
    float e = __expf(2.0f * x);
    return 1.0f - 2.0f * rcp_(e + 1.0f);   // saturates correctly (rcp(inf)=0)
}

template<bool F32>
__device__ __forceinline__ float ldin(const void* p, long i) {
    if constexpr (F32) return ((const float*)p)[i];
    else               return __bfloat162float(((const __hip_bfloat16*)p)[i]);
}
template<bool F32>
__device__ __forceinline__ void stout(void* p, long i, float v) {
    if constexpr (F32) ((float*)p)[i] = v;
    else               ((__hip_bfloat16*)p)[i] = __float2bfloat16(v);
}

// MFMA wrappers. K16 legacy builtin guarded: the K32 fallback with zero-padded
// element slots is exactly equivalent (A/B share the (lane,elem)->k labeling).
__device__ __forceinline__ v4f mfma_k32(v8hf a, v8hf b, v4f c) {
    return __builtin_amdgcn_mfma_f32_16x16x32_f16(a, b, c, 0, 0, 0);
}
__device__ __forceinline__ v4f mfma_k16(v4hf a, v4hf b, v4f c) {
#if __has_builtin(__builtin_amdgcn_mfma_f32_16x16x16f16)
    return __builtin_amdgcn_mfma_f32_16x16x16f16(a, b, c, 0, 0, 0);
#else
    v8hf a8; v8hf b8;
    #pragma unroll
    for (int j = 0; j < 4; ++j) { a8[j] = a[j]; b8[j] = b[j]; }
    #pragma unroll
    for (int j = 4; j < 8; ++j) { a8[j] = (_Float16)0.f; b8[j] = (_Float16)0.f; }
    return __builtin_amdgcn_mfma_f32_16x16x32_f16(a8, b8, c, 0, 0, 0);
#endif
}

// ---- prep body (templated on dtype), writes permuted rows ----
template<bool F32>
__device__ __forceinline__ void prep_body(const void* W_in, const void* b_in,
                                          const void* W_out, const void* b_out,
                                          const void* W_ih, const void* W_hh,
                                          const void* b_ih, const void* b_hh,
                                          float* ws, int j)
{
    if (j >= 128) return;
    const int gate = j >> 5;
    const int u    = j & 31;
    const int qb   = u >> 3;
    const int psi  = u & 7;
    const int tt   = 2*gate + (psi >> 2);
    const int p    = 16*tt + 4*qb + (psi & 3);

    float wx[14];
    #pragma unroll
    for (int c = 0; c < 14; ++c) wx[c] = 0.0f;
    float bg = ldin<F32>(b_ih, j) + ldin<F32>(b_hh, j);
    #pragma unroll
    for (int m = 0; m < 32; ++m) {
        float wihm = ldin<F32>(W_ih, j*32 + m);
        #pragma unroll
        for (int c = 0; c < 14; ++c) wx[c] = fmaf(wihm, ldin<F32>(W_in, m*14 + c), wx[c]);
        bg = fmaf(wihm, ldin<F32>(b_in, m), bg);
    }
    float a0 = wx[0];
    #pragma unroll
    for (int k = 0; k < 32; ++k)
        ws[p*32 + k] = ldin<F32>(W_hh, j*32 + k) + a0 * ldin<F32>(W_out, k);
    float bo = ldin<F32>(b_out, 0);
    const float bg2 = bg + a0 * bo;
    #pragma unroll
    for (int f = 0; f < 16; ++f)
        ws[4096 + p*16 + f] = (f < 13) ? wx[1 + f] : (f == 13 ? bg2 : 0.0f);
    ws[6272 + p] = a0;
    if (j < 32) ws[6528 + j] = ldin<F32>(W_out, j);   // unit-indexed
    if (j == 0) ws[6560] = bo;
}

// ---- fused detect + prep: one launch ----
__global__ void prep_all(const unsigned short* __restrict__ feat_raw,
                         const void* __restrict__ W_in,  const void* __restrict__ b_in,
                         const void* __restrict__ W_out, const void* __restrict__ b_out,
                         const void* __restrict__ W_ih,  const void* __restrict__ W_hh,
                         const void* __restrict__ b_ih,  const void* __restrict__ b_hh,
                         float* __restrict__ ws)
{
    __shared__ int cnt;
    const int tid = threadIdx.x;   // 0..127
    if (tid == 0) cnt = 0;
    __syncthreads();
    int insane = 0;
    for (int i = tid; i < 4096; i += 128) {
        float v = __uint_as_float(((unsigned int)feat_raw[i]) << 16);
        if (!(fabsf(v) < 1e8f)) insane++;
    }
    if (insane) atomicAdd(&cnt, insane);
    __syncthreads();
    const bool f32 = (cnt > 8);
    if (tid == 0) ws[FLAG_OFF] = f32 ? 1.0f : 0.0f;
    if (f32) prep_body<true >(W_in,b_in,W_out,b_out,W_ih,W_hh,b_ih,b_hh,ws,tid);
    else     prep_body<false>(W_in,b_in,W_out,b_out,W_ih,W_hh,b_ih,b_hh,ws,tid);
}

// ---- main LSTM body: h recirculates in-register; weights in LDS as packed
// fp16 fragment planes (per tile tt, stride 768 u32):
//   +0 whi0[lane*4] (uint4=v8hf)  +256 wlo0[lane*4]
//   +512 whi1[lane*2] (uint2=v4hf) +640 wlo1[lane*2]
// Reads are 16B/lane (8B for k16) contiguous -> conflict-free ds_read.
// Split-half: group G processes tiles {G,2+G,4+G,6+G} = gates i/f/g/o of
// cells psi=4G+r, finishing them before group G+1 -> only 4 acc tiles live.
template<bool F32>
__device__ __forceinline__ void lstm_body(const void* __restrict__ pm25,
                                          const void* __restrict__ feat,
                                          const float* __restrict__ ws,
                                          void* __restrict__ out)
{
    __shared__ __align__(16) unsigned sfrag[6144];   // 24 KB
    const int tid  = threadIdx.x;
    const int lane = tid & 63;
    const int rho  = lane & 15;      // seq within wave / A-row / D-col
    const int q    = lane >> 4;      // k-block / D-row-block / unit-block
    const int wv   = tid >> 6;
    const int wseq = (blockIdx.x*4 + wv) * 16;
    const int seq  = wseq + rho;
    const int bb   = seq / CITY_;
    const int city = seq - bb*CITY_;

    // ---- pack fp16 fragment planes into LDS (once per block).  RNE
    // conversions identical to the per-wave register path -> bit-identical.
    {
        const int L  = tid & 63;
        const int r2 = L & 15, q2 = L >> 4;
        #pragma unroll
        for (int k = 0; k < 2; ++k) {
            const int tt = (tid >> 6) * 2 + k;          // waves 0..3 x 2 tiles
            const float* src = ws + (16*tt + r2)*32 + 8*q2;
            unsigned* d0 = sfrag + tt*768 + L*4;
            #pragma unroll
            for (int m = 0; m < 4; ++m) {
                const float wA = src[2*m], wB = src[2*m+1];
                const _Float16 hA = (_Float16)wA, hB = (_Float16)wB;
                d0[m] = pack2(hA, hB);
                if constexpr (F32) {
                    (sfrag + tt*768 + 256 + L*4)[m] =
                        pack2((_Float16)(wA - (float)hA), (_Float16)(wB - (float)hB));
                }
            }
            const float* srcf = ws + 4096 + (16*tt + r2)*16 + 4*q2;
            unsigned* d2 = sfrag + tt*768 + 512 + L*2;
            #pragma unroll
            for (int m = 0; m < 2; ++m) {
                const float wA = srcf[2*m], wB = srcf[2*m+1];
                const _Float16 hA = (_Float16)wA, hB = (_Float16)wB;
                d2[m] = pack2(hA, hB);
                if constexpr (F32) {
                    (sfrag + tt*768 + 640 + L*2)[m] =
                        pack2((_Float16)(wA - (float)hA), (_Float16)(wB - (float)hB));
                }
            }
        }
    }
    __syncthreads();

    float wo8[8];
    #pragma unroll
    for (int j = 0; j < 8; ++j) wo8[j] = ws[6528 + 8*q + j]; // wout[unit 8q+j]
    const float bo = ws[6560];
    const long obase = (long)bb*PRED_*CITY_ + city;

    // ---- per-lane direct feature loads: elems 4q..4q+3.
    // elem 13 = constant 1.0 (bias column); 14,15 = 0.
    long fbase = ((long)(bb*(HIST_+PRED_) + HIST_)*CITY_ + city)*FEAT_;
    float fn[4];
    auto ldfeat = [&]() {            // prefetch one step's 4 elems into regs
        #pragma unroll
        for (int j = 0; j < 4; ++j) {
            const int e = 4*q + j;
            fn[j] = (e < FEAT_) ? ldin<F32>(feat, fbase + e)
                                : (e == FEAT_ ? 1.0f : 0.0f);
        }
        fbase += CITY_ * FEAT_;
    };
    v4hf fhi, flo;
    auto convf = [&]() {             // fn (raw) -> fp16 fragment(s)
        #pragma unroll
        for (int jj = 0; jj < 2; ++jj) {
            const v2hf ph = pkrtz(fn[2*jj], fn[2*jj+1]);
            fhi[2*jj] = ph[0]; fhi[2*jj+1] = ph[1];
            if constexpr (F32) {
                const v2hf pl = pkrtz(fn[2*jj] - (float)ph[0],
                                      fn[2*jj+1] - (float)ph[1]);
                flo[2*jj] = pl[0]; flo[2*jj+1] = pl[1];
            }
        }
    };

    float cst[8];                    // c-state, units 8q+psi, seq rho
    v8hf  xhi, xlo;                  // h: next step's B chunk0 (in-lane!)

    // finish one half-group: acc[k][r] = gate k (i/f/g/o) of cell psi=4G+r
    auto finish_half = [&](v4f (&acc)[4], float (&h)[8], int G, auto T0flag) {
        constexpr bool T0 = decltype(T0flag)::value;
        #pragma unroll
        for (int r = 0; r < 4; ++r) {
            const int psi = 4*G + r;
            const float I  = sigf(acc[0][r]);
            const float Gt = tanhf_(acc[2][r]);
            const float O  = sigf(acc[3][r]);
            float c;
            if constexpr (T0) c = I*Gt;
            else              c = fmaf(sigf(acc[1][r]), cst[psi], I*Gt);
            cst[psi] = c;
            h[psi] = O * tanhf_(c);
        }
    };
    auto pack_store = [&](float (&h)[8], int t) {
        #pragma unroll
        for (int jj = 0; jj < 4; ++jj) {   // pack -> next B fragment
            const v2hf ph = pkrtz(h[2*jj], h[2*jj+1]);
            xhi[2*jj] = ph[0]; xhi[2*jj+1] = ph[1];
            if constexpr (F32) {           // lo exactly compensates RTZ
                const v2hf pl = pkrtz(h[2*jj] - (float)ph[0],
                                      h[2*jj+1] - (float)ph[1]);
                xlo[2*jj] = pl[0]; xlo[2*jj+1] = pl[1];
            }
        }
        float y = 0.0f;                    // y_t = wout . h + bout
        #pragma unroll
        for (int psi = 0; psi < 8; ++psi) y = fmaf(wo8[psi], h[psi], y);
        y += __shfl_xor(y, 16);
        y += __shfl_xor(y, 32);
        if (q == 0) stout<F32>(out, obase + (long)t*CITY_, y + bo);
    };

    // ---- t = 0 : gates = a0*(x0-bo) (C-init) + Wf.[feat;1]  (h0 = 0) ----
    ldfeat();            // fn = feats(0)
    convf();             // fhi = feats(0)
    ldfeat();            // fn = feats(1) in flight
    {
        const float x0 = ldin<F32>(pm25, (long)(bb*HIST_ + (HIST_-1))*CITY_ + city);
        const float x0b = x0 - bo;
        float h[8];
        #pragma unroll
        for (int G = 0; G < 2; ++G) {
            v4f acc[4];
            #pragma unroll
            for (int k = 0; k < 4; ++k) {
                const int tt = 2*k + G;
                const v4f a0 = *(const v4f*)(ws + 6272 + 16*tt + 4*q);
                v4f c;
                #pragma unroll
                for (int r = 0; r < 4; ++r) c[r] = a0[r] * x0b;
                const v4hf whi1 = __builtin_bit_cast(
                    v4hf, *(const uint2*)(sfrag + tt*768 + 512 + lane*2));
                v4f a = mfma_k16(whi1, fhi, c);
                if constexpr (F32) {
                    const v4hf wlo1 = __builtin_bit_cast(
                        v4hf, *(const uint2*)(sfrag + tt*768 + 640 + lane*2));
                    a = mfma_k16(wlo1, fhi, a);
                    a = mfma_k16(whi1, flo, a);
                }
                acc[k] = a;
            }
            finish_half(acc, h, G, TrueT{});
        }
        pack_store(h, 0);
    }

    // ---- t = 1..23 ----
    const v4f zacc = {0.0f, 0.0f, 0.0f, 0.0f};
    #pragma unroll 1
    for (int t = 1; t < PRED_; ++t) {
        convf();                        // fhi = feats(t) (loaded last iter)
        if (t < PRED_-1) ldfeat();      // fn = feats(t+1)
        float h[8];
        #pragma unroll
        for (int G = 0; G < 2; ++G) {
            v4f acc[4];
            #pragma unroll
            for (int k = 0; k < 4; ++k) {
                const int tt = 2*k + G;
                const v8hf whi0 = __builtin_bit_cast(
                    v8hf, *(const uint4*)(sfrag + tt*768 + lane*4));
                const v4hf whi1 = __builtin_bit_cast(
                    v4hf, *(const uint2*)(sfrag + tt*768 + 512 + lane*2));
                v4f a = mfma_k32(whi0, xhi, zacc);
                if constexpr (F32) {
                    const v8hf wlo0 = __builtin_bit_cast(
                        v8hf, *(const uint4*)(sfrag + tt*768 + 256 + lane*4));
                    a = mfma_k32(wlo0, xhi, a);
                    a = mfma_k32(whi0, xlo, a);
                }
                a = mfma_k16(whi1, fhi, a);
                if constexpr (F32) {
                    const v4hf wlo1 = __builtin_bit_cast(
                        v4hf, *(const uint2*)(sfrag + tt*768 + 640 + lane*2));
                    a = mfma_k16(wlo1, fhi, a);
                    a = mfma_k16(whi1, flo, a);
                }
                acc[k] = a;
            }
            finish_half(acc, h, G, FalseT{});
        }
        pack_store(h, t);
    }
}

// Both kernels: cap 170 (3 waves/EU min).  Split-half keeps the unified
// VGPR+AGPR working set under the cap; WRITE_SIZE is the spill tripwire.
__global__ __launch_bounds__(256, 3) void lstm_bf16(
    const void* __restrict__ pm25, const void* __restrict__ feat,
    const float* __restrict__ ws,  void* __restrict__ out)
{
    if (ws[FLAG_OFF] != 0.0f) return;
    lstm_body<false>(pm25, feat, ws, out);
}

__global__ __launch_bounds__(256, 3) void lstm_f32(
    const void* __restrict__ pm25, const void* __restrict__ feat,
    const float* __restrict__ ws,  void* __restrict__ out)
{
    if (ws[FLAG_OFF] != 1.0f) return;
    lstm_body<true>(pm25, feat, ws, out);
}

extern "C" void kernel_launch(void* const* d_in, const int* in_sizes, int n_in,
                              void* d_out, int out_size, void* d_ws, size_t ws_size,
                              hipStream_t stream) {
    const void* pm25  = d_in[0];
    const void* feat  = d_in[1];
    const void* W_in  = d_in[2];
    const void* b_in  = d_in[3];
    const void* W_out = d_in[4];
    const void* b_out = d_in[5];
    const void* W_ih  = d_in[6];
    const void* W_hh  = d_in[7];
    const void* b_ih  = d_in[8];
    const void* b_hh  = d_in[9];
    float* ws = (float*)d_ws;

    prep_all<<<dim3(1), dim3(128), 0, stream>>>(
        (const unsigned short*)feat, W_in, b_in, W_out, b_out,
        W_ih, W_hh, b_ih, b_hh, ws);

    lstm_bf16<<<dim3(BC_/64), dim3(256), 0, stream>>>(pm25, feat, ws, d_out);
    lstm_f32 <<<dim3(BC_/64), dim3(256), 0, stream>>>(pm25, feat, ws, d_out);
}